// Round 1
// baseline (358.140 us; speedup 1.0000x reference)
//
#include <hip/hip_runtime.h>

#define Bb 4
#define Nn 4096
#define Dd 256
#define Hh 4
#define HDd 64
#define FFf 512
#define MT 16384  // B*N

typedef __attribute__((ext_vector_type(8))) short short8;
typedef __attribute__((ext_vector_type(4))) float f32x4;
typedef unsigned short u16;
typedef unsigned int u32;

__device__ __forceinline__ u16 f2bf(float f) {
    union { float f; u32 i; } v; v.f = f;
    u32 r = v.i + 0x7FFFu + ((v.i >> 16) & 1u);
    return (u16)(r >> 16);
}

__device__ __forceinline__ short8 ld8(const u16* p) {
    return *(const short8*)p;
}

// ---------------- weight prep: transpose + bf16 cast ----------------
// WqkvT [768][256], WoT [256][256], W1T [512][256], W2T [256][512]
__global__ __launch_bounds__(256) void prep_kernel(
        const float* __restrict__ Wq, const float* __restrict__ Wk,
        const float* __restrict__ Wv, const float* __restrict__ Wo,
        const float* __restrict__ W1, const float* __restrict__ W2,
        u16* __restrict__ WqkvT, u16* __restrict__ WoT,
        u16* __restrict__ W1T, u16* __restrict__ W2T) {
    int e = blockIdx.x * 256 + threadIdx.x;
    if (e < 196608) {                    // 768*256
        int c = e >> 8, k = e & 255;
        int mat = c >> 8;                // 0=q,1=k,2=v
        int cc = c & 255;
        const float* W = (mat == 0) ? Wq : ((mat == 1) ? Wk : Wv);
        WqkvT[(size_t)c * 256 + k] = f2bf(W[k * 256 + cc]);
    } else if (e < 262144) {             // +65536
        int i = e - 196608; int n = i >> 8, k = i & 255;
        WoT[n * 256 + k] = f2bf(Wo[k * 256 + n]);
    } else if (e < 393216) {             // +131072 (W1 [256][512])
        int i = e - 262144; int n = i >> 8, k = i & 255;
        W1T[n * 256 + k] = f2bf(W1[k * 512 + n]);
    } else {                             // +131072 (W2 [512][256])
        int i = e - 393216; int n = i >> 9, k = i & 511;
        W2T[n * 512 + k] = f2bf(W2[k * 256 + n]);
    }
}

// ---------------- LayerNorm: one wave per row of 256 ----------------
__global__ __launch_bounds__(256) void ln_kernel(const float* __restrict__ x,
        const float* __restrict__ w, const float* __restrict__ bia,
        u16* __restrict__ out) {
    int lane = threadIdx.x & 63;
    int row = blockIdx.x * 4 + (threadIdx.x >> 6);
    const float* xr = x + (size_t)row * Dd;
    float4 v = *(const float4*)(xr + lane * 4);
    float s = v.x + v.y + v.z + v.w;
    float s2 = v.x * v.x + v.y * v.y + v.z * v.z + v.w * v.w;
    #pragma unroll
    for (int off = 1; off < 64; off <<= 1) {
        s  += __shfl_xor(s, off);
        s2 += __shfl_xor(s2, off);
    }
    float mu = s * (1.0f / Dd);
    float var = s2 * (1.0f / Dd) - mu * mu;
    float rstd = rsqrtf(var + 1e-5f);
    float4 wv = *(const float4*)(w + lane * 4);
    float4 bv = *(const float4*)(bia + lane * 4);
    ushort4 ov;
    ov.x = f2bf((v.x - mu) * rstd * wv.x + bv.x);
    ov.y = f2bf((v.y - mu) * rstd * wv.y + bv.y);
    ov.z = f2bf((v.z - mu) * rstd * wv.z + bv.z);
    ov.w = f2bf((v.w - mu) * rstd * wv.w + bv.w);
    *(ushort4*)(out + (size_t)row * Dd + lane * 4) = ov;
}

// ---------------- GEMM: A[M,K] bf16 x BT[N,K] bf16 -> epilogue ----------------
// 128x128 tile, BK=32, 4 waves (2x2), each wave 64x64 = 4x4 mfma 16x16x32.
// MODE 0: QKV (writes q [bh][n][64], k [bh][n][64], vT [bh][64][n])
// MODE 1: out-proj: outf = resid + acc + bias0   (f32)
// MODE 2: FFN1: o0 = bf16(gelu(acc + bias0)), stride FFf
// MODE 3: FFN2: outf = resid + acc + bias0   (f32)
template<int MODE, int KD>
__global__ __launch_bounds__(256) void gemm_bt(
        const u16* __restrict__ A, const u16* __restrict__ BT,
        const float* __restrict__ bias0, const float* __restrict__ bias1,
        const float* __restrict__ bias2,
        const float* __restrict__ resid, float* __restrict__ outf,
        u16* __restrict__ o0, u16* __restrict__ o1, u16* __restrict__ o2) {
    __shared__ u16 Asl[128 * 32];
    __shared__ u16 Bsl[128 * 32];
    int lane = threadIdx.x & 63;
    int wv = threadIdx.x >> 6;
    int wm = wv >> 1, wn = wv & 1;
    int m0 = blockIdx.y * 128, n0 = blockIdx.x * 128;
    f32x4 zz; zz[0] = 0.f; zz[1] = 0.f; zz[2] = 0.f; zz[3] = 0.f;
    f32x4 acc[4][4];
    #pragma unroll
    for (int i = 0; i < 4; ++i)
        #pragma unroll
        for (int j = 0; j < 4; ++j) acc[i][j] = zz;

    for (int kt = 0; kt < KD; kt += 32) {
        __syncthreads();
        #pragma unroll
        for (int i = 0; i < 2; ++i) {
            int chunk = threadIdx.x + i * 256;
            int row = chunk >> 2, c16 = chunk & 3;
            int lofs = row * 32 + ((c16 * 8) ^ ((row & 3) * 8));
            *(uint4*)(Asl + lofs) = *(const uint4*)(A + (size_t)(m0 + row) * KD + kt + c16 * 8);
            *(uint4*)(Bsl + lofs) = *(const uint4*)(BT + (size_t)(n0 + row) * KD + kt + c16 * 8);
        }
        __syncthreads();
        short8 af[4], bfr[4];
        #pragma unroll
        for (int t = 0; t < 4; ++t) {
            int arow = wm * 64 + t * 16 + (lane & 15);
            af[t]  = ld8(Asl + arow * 32 + (((lane >> 4) * 8) ^ ((arow & 3) * 8)));
            int brow = wn * 64 + t * 16 + (lane & 15);
            bfr[t] = ld8(Bsl + brow * 32 + (((lane >> 4) * 8) ^ ((brow & 3) * 8)));
        }
        #pragma unroll
        for (int mt = 0; mt < 4; ++mt)
            #pragma unroll
            for (int nt = 0; nt < 4; ++nt)
                acc[mt][nt] = __builtin_amdgcn_mfma_f32_16x16x32_bf16(af[mt], bfr[nt], acc[mt][nt], 0, 0, 0);
    }

    #pragma unroll
    for (int mt = 0; mt < 4; ++mt) {
        #pragma unroll
        for (int nt = 0; nt < 4; ++nt) {
            #pragma unroll
            for (int r = 0; r < 4; ++r) {
                int row = m0 + wm * 64 + mt * 16 + (lane >> 4) * 4 + r;
                int col = n0 + wn * 64 + nt * 16 + (lane & 15);
                float v = acc[mt][nt][r];
                if (MODE == 0) {
                    int mat = col >> 8;
                    int cc = col & 255;
                    int hh = cc >> 6, dd = cc & 63;
                    int bbi = row >> 12, nni = row & 4095;
                    int bh = bbi * Hh + hh;
                    if (mat == 0)      o0[((size_t)bh * Nn + nni) * HDd + dd] = f2bf(v + bias0[cc]);
                    else if (mat == 1) o1[((size_t)bh * Nn + nni) * HDd + dd] = f2bf(v + bias1[cc]);
                    else               o2[((size_t)bh * HDd + dd) * Nn + nni] = f2bf(v + bias2[cc]);
                } else if (MODE == 1) {
                    outf[(size_t)row * Dd + col] = resid[(size_t)row * Dd + col] + v + bias0[col];
                } else if (MODE == 2) {
                    float xg = v + bias0[col];
                    float g = 0.5f * xg * (1.0f + erff(xg * 0.70710678118654752f));
                    o0[(size_t)row * FFf + col] = f2bf(g);
                } else {
                    outf[(size_t)row * Dd + col] = resid[(size_t)row * Dd + col] + v + bias0[col];
                }
            }
        }
    }
}

// ---------------- Flash attention ----------------
// grid: 16 (b,h) * 32 q-tiles of 128 rows. 4 waves, each 32 q rows.
// K tile [64 keys][64 d] and V^T tile [64 d][64 keys] in XOR-swizzled LDS.
__global__ __launch_bounds__(256) void attn_kernel(
        const u16* __restrict__ Qb, const u16* __restrict__ Kb,
        const u16* __restrict__ VTb, const float* __restrict__ imp,
        u16* __restrict__ ctxOut) {
    __shared__ u16 Klds[64 * 64];
    __shared__ u16 Vlds[64 * 64];
    __shared__ float implds[64];
    __shared__ u16 Plds[4][32 * 64];
    int lane = threadIdx.x & 63;
    int wv = threadIdx.x >> 6;
    int bh = blockIdx.x >> 5;
    int qt = blockIdx.x & 31;
    int bbi = bh >> 2, hh = bh & 3;
    int qrow0 = qt * 128 + wv * 32;

    short8 qa[2][2];
    #pragma unroll
    for (int mt = 0; mt < 2; ++mt) {
        const u16* qp = Qb + ((size_t)bh * Nn + qrow0 + mt * 16 + (lane & 15)) * HDd + (lane >> 4) * 8;
        qa[mt][0] = ld8(qp);
        qa[mt][1] = ld8(qp + 32);
    }
    f32x4 zz; zz[0] = 0.f; zz[1] = 0.f; zz[2] = 0.f; zz[3] = 0.f;
    float mrow[2][4], lrow[2][4];
    f32x4 ctx[2][4];
    #pragma unroll
    for (int mt = 0; mt < 2; ++mt) {
        #pragma unroll
        for (int r = 0; r < 4; ++r) { mrow[mt][r] = -__builtin_inff(); lrow[mt][r] = 0.f; }
        #pragma unroll
        for (int ct = 0; ct < 4; ++ct) ctx[mt][ct] = zz;
    }

    for (int kt = 0; kt < Nn; kt += 64) {
        __syncthreads();
        #pragma unroll
        for (int i = 0; i < 2; ++i) {
            int chunk = threadIdx.x + i * 256;
            int row = chunk >> 3, c16 = chunk & 7;
            int lofs = row * 64 + ((c16 * 8) ^ ((row & 7) * 8));
            *(uint4*)(Klds + lofs) = *(const uint4*)(Kb + ((size_t)bh * Nn + kt + row) * HDd + c16 * 8);
            *(uint4*)(Vlds + lofs) = *(const uint4*)(VTb + ((size_t)bh * HDd + row) * Nn + kt + c16 * 8);
        }
        if (threadIdx.x < 64) implds[threadIdx.x] = imp[(size_t)bbi * Nn + kt + threadIdx.x];
        __syncthreads();

        short8 kf[4][2];
        #pragma unroll
        for (int st = 0; st < 4; ++st) {
            int krow = st * 16 + (lane & 15);
            #pragma unroll
            for (int kk = 0; kk < 2; ++kk)
                kf[st][kk] = ld8(Klds + krow * 64 + ((((lane >> 4) * 8) + kk * 32) ^ ((krow & 7) * 8)));
        }
        float impv[4];
        #pragma unroll
        for (int st = 0; st < 4; ++st) impv[st] = implds[st * 16 + (lane & 15)];

        #pragma unroll
        for (int mt = 0; mt < 2; ++mt) {
            f32x4 sacc[4];
            #pragma unroll
            for (int st = 0; st < 4; ++st) {
                f32x4 z = zz;
                z = __builtin_amdgcn_mfma_f32_16x16x32_bf16(qa[mt][0], kf[st][0], z, 0, 0, 0);
                z = __builtin_amdgcn_mfma_f32_16x16x32_bf16(qa[mt][1], kf[st][1], z, 0, 0, 0);
                sacc[st] = z;
            }
            #pragma unroll
            for (int r = 0; r < 4; ++r) {
                float sv[4]; float tm = -__builtin_inff();
                #pragma unroll
                for (int st = 0; st < 4; ++st) {
                    sv[st] = sacc[st][r] * 0.125f + impv[st];
                    tm = fmaxf(tm, sv[st]);
                }
                tm = fmaxf(tm, __shfl_xor(tm, 1));
                tm = fmaxf(tm, __shfl_xor(tm, 2));
                tm = fmaxf(tm, __shfl_xor(tm, 4));
                tm = fmaxf(tm, __shfl_xor(tm, 8));
                float nm = fmaxf(mrow[mt][r], tm);
                float p[4]; float rs = 0.f;
                #pragma unroll
                for (int st = 0; st < 4; ++st) { p[st] = __expf(sv[st] - nm); rs += p[st]; }
                rs += __shfl_xor(rs, 1);
                rs += __shfl_xor(rs, 2);
                rs += __shfl_xor(rs, 4);
                rs += __shfl_xor(rs, 8);
                float alpha = __expf(mrow[mt][r] - nm);
                lrow[mt][r] = lrow[mt][r] * alpha + rs;
                mrow[mt][r] = nm;
                #pragma unroll
                for (int ct = 0; ct < 4; ++ct) ctx[mt][ct][r] *= alpha;
                int prow = mt * 16 + (lane >> 4) * 4 + r;
                #pragma unroll
                for (int st = 0; st < 4; ++st) {
                    int pcol = st * 16 + (lane & 15);
                    Plds[wv][prow * 64 + (pcol ^ ((prow & 7) * 8))] = f2bf(p[st]);
                }
            }
        }

        #pragma unroll
        for (int kk = 0; kk < 2; ++kk) {
            short8 pf[2];
            #pragma unroll
            for (int mt = 0; mt < 2; ++mt) {
                int prow = mt * 16 + (lane & 15);
                pf[mt] = ld8(Plds[wv] + prow * 64 + ((((lane >> 4) * 8) + kk * 32) ^ ((prow & 7) * 8)));
            }
            #pragma unroll
            for (int ct = 0; ct < 4; ++ct) {
                int vrow = ct * 16 + (lane & 15);
                short8 vf = ld8(Vlds + vrow * 64 + ((((lane >> 4) * 8) + kk * 32) ^ ((vrow & 7) * 8)));
                ctx[0][ct] = __builtin_amdgcn_mfma_f32_16x16x32_bf16(pf[0], vf, ctx[0][ct], 0, 0, 0);
                ctx[1][ct] = __builtin_amdgcn_mfma_f32_16x16x32_bf16(pf[1], vf, ctx[1][ct], 0, 0, 0);
            }
        }
    }

    #pragma unroll
    for (int mt = 0; mt < 2; ++mt) {
        #pragma unroll
        for (int r = 0; r < 4; ++r) {
            float inv = 1.0f / lrow[mt][r];
            int nglob = qrow0 + mt * 16 + (lane >> 4) * 4 + r;
            #pragma unroll
            for (int ct = 0; ct < 4; ++ct) {
                int dcol = hh * HDd + ct * 16 + (lane & 15);
                ctxOut[((size_t)bbi * Nn + nglob) * Dd + dcol] = f2bf(ctx[mt][ct][r] * inv);
            }
        }
    }
}

extern "C" void kernel_launch(void* const* d_in, const int* in_sizes, int n_in,
                              void* d_out, int out_size, void* d_ws, size_t ws_size,
                              hipStream_t stream) {
    (void)in_sizes; (void)n_in; (void)out_size; (void)ws_size;
    const float* tokens     = (const float*)d_in[0];
    const float* importance = (const float*)d_in[1];
    const float* n1w = (const float*)d_in[2];
    const float* n1b = (const float*)d_in[3];
    const float* Wq  = (const float*)d_in[4];
    const float* bq  = (const float*)d_in[5];
    const float* Wk  = (const float*)d_in[6];
    const float* bk  = (const float*)d_in[7];
    const float* Wv  = (const float*)d_in[8];
    const float* bv  = (const float*)d_in[9];
    const float* Wo  = (const float*)d_in[10];
    const float* bo  = (const float*)d_in[11];
    const float* n2w = (const float*)d_in[12];
    const float* n2b = (const float*)d_in[13];
    const float* W1  = (const float*)d_in[14];
    const float* b1  = (const float*)d_in[15];
    const float* W2  = (const float*)d_in[16];
    const float* b2  = (const float*)d_in[17];
    float* out = (float*)d_out;

    char* ws = (char*)d_ws;
    u16* xln   = (u16*)(ws);
    u16* qb    = (u16*)(ws + ((size_t)8 << 20));
    u16* kb    = (u16*)(ws + ((size_t)16 << 20));
    u16* vT    = (u16*)(ws + ((size_t)24 << 20));
    u16* ctx   = (u16*)(ws + ((size_t)32 << 20));
    float* x2  = (float*)(ws + ((size_t)40 << 20));
    u16* yln   = (u16*)(ws + ((size_t)56 << 20));
    u16* hbuf  = (u16*)(ws + ((size_t)64 << 20));
    u16* WqkvT = (u16*)(ws + ((size_t)80 << 20));
    u16* WoT   = (u16*)(ws + ((size_t)80 << 20) + 393216);
    u16* W1T   = (u16*)(ws + ((size_t)80 << 20) + 393216 + 131072);
    u16* W2T   = (u16*)(ws + ((size_t)80 << 20) + 393216 + 131072 + 262144);

    prep_kernel<<<2048, 256, 0, stream>>>(Wq, Wk, Wv, Wo, W1, W2, WqkvT, WoT, W1T, W2T);
    ln_kernel<<<4096, 256, 0, stream>>>(tokens, n1w, n1b, xln);
    gemm_bt<0, 256><<<dim3(6, 128), 256, 0, stream>>>(xln, WqkvT, bq, bk, bv,
                                                      nullptr, nullptr, qb, kb, vT);
    attn_kernel<<<512, 256, 0, stream>>>(qb, kb, vT, importance, ctx);
    gemm_bt<1, 256><<<dim3(2, 128), 256, 0, stream>>>(ctx, WoT, bo, nullptr, nullptr,
                                                      tokens, x2, nullptr, nullptr, nullptr);
    ln_kernel<<<4096, 256, 0, stream>>>(x2, n2w, n2b, yln);
    gemm_bt<2, 256><<<dim3(4, 128), 256, 0, stream>>>(yln, W1T, b1, nullptr, nullptr,
                                                      nullptr, nullptr, hbuf, nullptr, nullptr);
    gemm_bt<3, 512><<<dim3(2, 128), 256, 0, stream>>>(hbuf, W2T, b2, nullptr, nullptr,
                                                      x2, out, nullptr, nullptr, nullptr);
}

// Round 2
// 272.044 us; speedup vs baseline: 1.3165x; 1.3165x over previous
//
#include <hip/hip_runtime.h>

#define Bb 4
#define Nn 4096
#define Dd 256
#define Hh 4
#define HDd 64
#define FFf 512
#define MT 16384  // B*N

typedef __attribute__((ext_vector_type(8))) short short8;
typedef __attribute__((ext_vector_type(4))) float f32x4;
typedef __attribute__((ext_vector_type(16))) float f32x16;
typedef unsigned short u16;
typedef unsigned int u32;
typedef __attribute__((ext_vector_type(4))) u32 u32x4;

__device__ __forceinline__ u16 f2bf(float f) {
    union { float f; u32 i; } v; v.f = f;
    u32 r = v.i + 0x7FFFu + ((v.i >> 16) & 1u);
    return (u16)(r >> 16);
}

__device__ __forceinline__ short8 ld8(const u16* p) {
    return *(const short8*)p;
}

// v_permlane32_swap: a' = [a.lo, b.lo], b' = [a.hi, b.hi]
__device__ __forceinline__ void pl32swap(u32& a, u32& b) {
    asm("v_permlane32_swap_b32 %0, %1" : "+v"(a), "+v"(b));
}
__device__ __forceinline__ float xhalf_max(float x) {
    u32 a = __float_as_uint(x), b = a;
    pl32swap(a, b);
    return fmaxf(__uint_as_float(a), __uint_as_float(b));
}
__device__ __forceinline__ float xhalf_sum(float x) {
    u32 a = __float_as_uint(x), b = a;
    pl32swap(a, b);
    return __uint_as_float(a) + __uint_as_float(b);
}
__device__ __forceinline__ u32 cvtpk(float lo, float hi) {
    u32 r;
    asm("v_cvt_pk_bf16_f32 %0, %1, %2" : "=v"(r) : "v"(lo), "v"(hi));
    return r;
}

#define QSCALE 0.18033610062f  /* 0.125 * log2(e) */
#define LOG2E  1.44269504089f

// ---------------- weight prep: transpose + bf16 cast ----------------
__global__ __launch_bounds__(256) void prep_kernel(
        const float* __restrict__ Wq, const float* __restrict__ Wk,
        const float* __restrict__ Wv, const float* __restrict__ Wo,
        const float* __restrict__ W1, const float* __restrict__ W2,
        u16* __restrict__ WqkvT, u16* __restrict__ WoT,
        u16* __restrict__ W1T, u16* __restrict__ W2T) {
    int e = blockIdx.x * 256 + threadIdx.x;
    if (e < 196608) {                    // 768*256
        int c = e >> 8, k = e & 255;
        int mat = c >> 8;                // 0=q,1=k,2=v
        int cc = c & 255;
        const float* W = (mat == 0) ? Wq : ((mat == 1) ? Wk : Wv);
        WqkvT[(size_t)c * 256 + k] = f2bf(W[k * 256 + cc]);
    } else if (e < 262144) {
        int i = e - 196608; int n = i >> 8, k = i & 255;
        WoT[n * 256 + k] = f2bf(Wo[k * 256 + n]);
    } else if (e < 393216) {
        int i = e - 262144; int n = i >> 8, k = i & 255;
        W1T[n * 256 + k] = f2bf(W1[k * 512 + n]);
    } else {
        int i = e - 393216; int n = i >> 9, k = i & 511;
        W2T[n * 512 + k] = f2bf(W2[k * 256 + n]);
    }
}

// ---------------- LayerNorm ----------------
__global__ __launch_bounds__(256) void ln_kernel(const float* __restrict__ x,
        const float* __restrict__ w, const float* __restrict__ bia,
        u16* __restrict__ out) {
    int lane = threadIdx.x & 63;
    int row = blockIdx.x * 4 + (threadIdx.x >> 6);
    const float* xr = x + (size_t)row * Dd;
    float4 v = *(const float4*)(xr + lane * 4);
    float s = v.x + v.y + v.z + v.w;
    float s2 = v.x * v.x + v.y * v.y + v.z * v.z + v.w * v.w;
    #pragma unroll
    for (int off = 1; off < 64; off <<= 1) {
        s  += __shfl_xor(s, off);
        s2 += __shfl_xor(s2, off);
    }
    float mu = s * (1.0f / Dd);
    float var = s2 * (1.0f / Dd) - mu * mu;
    float rstd = rsqrtf(var + 1e-5f);
    float4 wv = *(const float4*)(w + lane * 4);
    float4 bv = *(const float4*)(bia + lane * 4);
    ushort4 ov;
    ov.x = f2bf((v.x - mu) * rstd * wv.x + bv.x);
    ov.y = f2bf((v.y - mu) * rstd * wv.y + bv.y);
    ov.z = f2bf((v.z - mu) * rstd * wv.z + bv.z);
    ov.w = f2bf((v.w - mu) * rstd * wv.w + bv.w);
    *(ushort4*)(out + (size_t)row * Dd + lane * 4) = ov;
}

// ---------------- GEMM: A[M,K] bf16 x BT[N,K] bf16 -> epilogue ----------------
template<int MODE, int KD>
__global__ __launch_bounds__(256) void gemm_bt(
        const u16* __restrict__ A, const u16* __restrict__ BT,
        const float* __restrict__ bias0, const float* __restrict__ bias1,
        const float* __restrict__ bias2,
        const float* __restrict__ resid, float* __restrict__ outf,
        u16* __restrict__ o0, u16* __restrict__ o1, u16* __restrict__ o2) {
    __shared__ u16 Asl[128 * 32];
    __shared__ u16 Bsl[128 * 32];
    int lane = threadIdx.x & 63;
    int wv = threadIdx.x >> 6;
    int wm = wv >> 1, wn = wv & 1;
    int m0 = blockIdx.y * 128, n0 = blockIdx.x * 128;
    f32x4 zz; zz[0] = 0.f; zz[1] = 0.f; zz[2] = 0.f; zz[3] = 0.f;
    f32x4 acc[4][4];
    #pragma unroll
    for (int i = 0; i < 4; ++i)
        #pragma unroll
        for (int j = 0; j < 4; ++j) acc[i][j] = zz;

    for (int kt = 0; kt < KD; kt += 32) {
        __syncthreads();
        #pragma unroll
        for (int i = 0; i < 2; ++i) {
            int chunk = threadIdx.x + i * 256;
            int row = chunk >> 2, c16 = chunk & 3;
            int lofs = row * 32 + ((c16 * 8) ^ ((row & 3) * 8));
            *(uint4*)(Asl + lofs) = *(const uint4*)(A + (size_t)(m0 + row) * KD + kt + c16 * 8);
            *(uint4*)(Bsl + lofs) = *(const uint4*)(BT + (size_t)(n0 + row) * KD + kt + c16 * 8);
        }
        __syncthreads();
        short8 af[4], bfr[4];
        #pragma unroll
        for (int t = 0; t < 4; ++t) {
            int arow = wm * 64 + t * 16 + (lane & 15);
            af[t]  = ld8(Asl + arow * 32 + (((lane >> 4) * 8) ^ ((arow & 3) * 8)));
            int brow = wn * 64 + t * 16 + (lane & 15);
            bfr[t] = ld8(Bsl + brow * 32 + (((lane >> 4) * 8) ^ ((brow & 3) * 8)));
        }
        #pragma unroll
        for (int mt = 0; mt < 4; ++mt)
            #pragma unroll
            for (int nt = 0; nt < 4; ++nt)
                acc[mt][nt] = __builtin_amdgcn_mfma_f32_16x16x32_bf16(af[mt], bfr[nt], acc[mt][nt], 0, 0, 0);
    }

    #pragma unroll
    for (int mt = 0; mt < 4; ++mt) {
        #pragma unroll
        for (int nt = 0; nt < 4; ++nt) {
            #pragma unroll
            for (int r = 0; r < 4; ++r) {
                int row = m0 + wm * 64 + mt * 16 + (lane >> 4) * 4 + r;
                int col = n0 + wn * 64 + nt * 16 + (lane & 15);
                float v = acc[mt][nt][r];
                if (MODE == 0) {
                    int mat = col >> 8;
                    int cc = col & 255;
                    int hh = cc >> 6, dd = cc & 63;
                    int bbi = row >> 12, nni = row & 4095;
                    int bh = bbi * Hh + hh;
                    // q pre-scaled by 0.125*log2(e) for exp2-domain flash attention
                    if (mat == 0)      o0[((size_t)bh * Nn + nni) * HDd + dd] = f2bf((v + bias0[cc]) * QSCALE);
                    else if (mat == 1) o1[((size_t)bh * Nn + nni) * HDd + dd] = f2bf(v + bias1[cc]);
                    else               o2[((size_t)bh * HDd + dd) * Nn + nni] = f2bf(v + bias2[cc]);
                } else if (MODE == 1) {
                    outf[(size_t)row * Dd + col] = resid[(size_t)row * Dd + col] + v + bias0[col];
                } else if (MODE == 2) {
                    float xg = v + bias0[col];
                    float g = 0.5f * xg * (1.0f + erff(xg * 0.70710678118654752f));
                    o0[(size_t)row * FFf + col] = f2bf(g);
                } else {
                    outf[(size_t)row * Dd + col] = resid[(size_t)row * Dd + col] + v + bias0[col];
                }
            }
        }
    }
}

// ---------------- Flash attention, swapped-operand 32x32x16 ----------------
// grid: 16 bh * 32 q-tiles(128). 4 waves, each 32 q-rows.
// Per wave: lane owns query column q=lane&31 (hf=lane>>5 selects k-groups).
// QK^T: S^T[key][q] = mfma(K_frag, Q_frag) (+1 augmented mfma adding imp[key]).
// Softmax fully in-register (permlane32_swap cross-half), P built via cvt_pk.
// PV: ctx^T[d][q] = mfma(VT_frag, P_frag).
__global__ __launch_bounds__(256) void attn_kernel(
        const u16* __restrict__ Qb, const u16* __restrict__ Kb,
        const u16* __restrict__ VTb, const float* __restrict__ imp,
        u16* __restrict__ ctxOut) {
    __shared__ u16 Klds[64 * 64];
    __shared__ u16 Vlds[64 * 64];
    __shared__ float Clds[4][32 * 64];
    int lane = threadIdx.x & 63;
    int wv = threadIdx.x >> 6;
    int bh = blockIdx.x >> 5;
    int qt = blockIdx.x & 31;
    int bbi = bh >> 2, hh = bh & 3;
    int qrow0 = qt * 128 + wv * 32;
    int q = lane & 31;
    int hf = lane >> 5;

    // Q B-frags (hoisted): lane holds Q[q][ks*16 + hf*8 .. +8]
    short8 qf[4];
    #pragma unroll
    for (int ks = 0; ks < 4; ++ks)
        qf[ks] = ld8(Qb + ((size_t)bh * Nn + qrow0 + q) * HDd + ks * 16 + hf * 8);

    // constant all-ones B-frag for the importance-augmentation mfma
    short8 onef = (short8)0;
    if (hf == 0) { onef[0] = (short)0x3F80; onef[1] = (short)0x3F80; }

    f32x16 ctx[2];
    #pragma unroll
    for (int r = 0; r < 16; ++r) { ctx[0][r] = 0.f; ctx[1][r] = 0.f; }
    float m = -__builtin_inff(), l = 0.f;

    for (int kt = 0; kt < Nn; kt += 64) {
        __syncthreads();
        #pragma unroll
        for (int i = 0; i < 2; ++i) {
            int c = threadIdx.x + i * 256;
            int row = c >> 3, c16 = c & 7;
            int dsw = row * 64 + ((c16 ^ (row & 7)) * 8);
            *(uint4*)(Klds + dsw) = *(const uint4*)(Kb + ((size_t)bh * Nn + kt + row) * HDd + c16 * 8);
            *(uint4*)(Vlds + dsw) = *(const uint4*)(VTb + ((size_t)bh * HDd + row) * Nn + kt + c16 * 8);
        }
        __syncthreads();

        #pragma unroll
        for (int st = 0; st < 2; ++st) {
            int krow = st * 32 + q;
            f32x16 s;
            #pragma unroll
            for (int r = 0; r < 16; ++r) s[r] = 0.f;
            __builtin_amdgcn_s_setprio(1);
            #pragma unroll
            for (int ks = 0; ks < 4; ++ks) {
                short8 kf = ld8(Klds + krow * 64 + (((ks * 2 + hf) ^ (krow & 7)) * 8));
                s = __builtin_amdgcn_mfma_f32_32x32x16_bf16(kf, qf[ks], s, 0, 0, 0);
            }
            __builtin_amdgcn_s_setprio(0);
            // augmented slice: adds imp[key]*log2e (split in 2 bf16 for precision)
            float ivs = imp[(size_t)bbi * Nn + kt + st * 32 + q] * LOG2E;
            u16 ih = f2bf(ivs);
            float rem = ivs - __uint_as_float(((u32)ih) << 16);
            u16 il = f2bf(rem);
            short8 af = (short8)0;
            if (hf == 0) { af[0] = (short)ih; af[1] = (short)il; }
            s = __builtin_amdgcn_mfma_f32_32x32x16_bf16(af, onef, s, 0, 0, 0);

            // ---- in-register online softmax (exp2 domain) ----
            float tm = s[0];
            #pragma unroll
            for (int r = 1; r < 16; ++r) tm = fmaxf(tm, s[r]);
            tm = xhalf_max(tm);
            bool nore = __all(tm <= m + 8.0f);
            if (!nore) {
                float nm = fmaxf(m, tm);
                float al = exp2f(m - nm);
                l *= al;
                #pragma unroll
                for (int r = 0; r < 16; ++r) { ctx[0][r] *= al; ctx[1][r] *= al; }
                m = nm;
            }
            float rs = 0.f;
            #pragma unroll
            for (int r = 0; r < 16; ++r) { float pv = exp2f(s[r] - m); s[r] = pv; rs += pv; }
            l += xhalf_sum(rs);

            // ---- P -> bf16 B-frags in-register ----
            u32 w[8];
            #pragma unroll
            for (int j = 0; j < 8; ++j) w[j] = cvtpk(s[2 * j], s[2 * j + 1]);
            pl32swap(w[0], w[2]); pl32swap(w[1], w[3]);
            pl32swap(w[4], w[6]); pl32swap(w[5], w[7]);
            u32x4 t0; t0[0] = w[0]; t0[1] = w[1]; t0[2] = w[2]; t0[3] = w[3];
            u32x4 t1; t1[0] = w[4]; t1[1] = w[5]; t1[2] = w[6]; t1[3] = w[7];
            short8 pf0 = __builtin_bit_cast(short8, t0);
            short8 pf1 = __builtin_bit_cast(short8, t1);

            // ---- PV: ctx^T[d][q] += V^T frags x P ----
            __builtin_amdgcn_s_setprio(1);
            #pragma unroll
            for (int dt = 0; dt < 2; ++dt) {
                int vrow = dt * 32 + q;
                short8 vf0 = ld8(Vlds + vrow * 64 + (((st * 4 + hf) ^ (vrow & 7)) * 8));
                ctx[dt] = __builtin_amdgcn_mfma_f32_32x32x16_bf16(vf0, pf0, ctx[dt], 0, 0, 0);
                short8 vf1 = ld8(Vlds + vrow * 64 + (((st * 4 + 2 + hf) ^ (vrow & 7)) * 8));
                ctx[dt] = __builtin_amdgcn_mfma_f32_32x32x16_bf16(vf1, pf1, ctx[dt], 0, 0, 0);
            }
            __builtin_amdgcn_s_setprio(0);
        }
    }

    // ---- epilogue: normalize, transpose via LDS, coalesced store ----
    float inv = 1.0f / l;
    #pragma unroll
    for (int dt = 0; dt < 2; ++dt) {
        #pragma unroll
        for (int r = 0; r < 16; ++r) {
            int d = dt * 32 + (r & 3) + 8 * (r >> 2) + 4 * hf;
            Clds[wv][q * 64 + (d ^ ((q & 7) << 2))] = ctx[dt][r] * inv;
        }
    }
    u16* op = ctxOut + ((size_t)bbi * Nn + qrow0 + q) * Dd + hh * HDd + hf * 32;
    #pragma unroll
    for (int gp = 0; gp < 4; ++gp) {
        int gi0 = hf * 8 + gp * 2, gi1 = gi0 + 1;
        int g0 = (gi0 & 8) | ((gi0 & 7) ^ (q & 7));
        int g1 = (gi1 & 8) | ((gi1 & 7) ^ (q & 7));
        float4 v0 = *(const float4*)(&Clds[wv][q * 64 + g0 * 4]);
        float4 v1 = *(const float4*)(&Clds[wv][q * 64 + g1 * 4]);
        uint4 pk;
        pk.x = cvtpk(v0.x, v0.y); pk.y = cvtpk(v0.z, v0.w);
        pk.z = cvtpk(v1.x, v1.y); pk.w = cvtpk(v1.z, v1.w);
        *(uint4*)(op + gp * 8) = pk;
    }
}

extern "C" void kernel_launch(void* const* d_in, const int* in_sizes, int n_in,
                              void* d_out, int out_size, void* d_ws, size_t ws_size,
                              hipStream_t stream) {
    (void)in_sizes; (void)n_in; (void)out_size; (void)ws_size;
    const float* tokens     = (const float*)d_in[0];
    const float* importance = (const float*)d_in[1];
    const float* n1w = (const float*)d_in[2];
    const float* n1b = (const float*)d_in[3];
    const float* Wq  = (const float*)d_in[4];
    const float* bq  = (const float*)d_in[5];
    const float* Wk  = (const float*)d_in[6];
    const float* bk  = (const float*)d_in[7];
    const float* Wv  = (const float*)d_in[8];
    const float* bv  = (const float*)d_in[9];
    const float* Wo  = (const float*)d_in[10];
    const float* bo  = (const float*)d_in[11];
    const float* n2w = (const float*)d_in[12];
    const float* n2b = (const float*)d_in[13];
    const float* W1  = (const float*)d_in[14];
    const float* b1  = (const float*)d_in[15];
    const float* W2  = (const float*)d_in[16];
    const float* b2  = (const float*)d_in[17];
    float* out = (float*)d_out;

    char* ws = (char*)d_ws;
    u16* xln   = (u16*)(ws);
    u16* qb    = (u16*)(ws + ((size_t)8 << 20));
    u16* kb    = (u16*)(ws + ((size_t)16 << 20));
    u16* vT    = (u16*)(ws + ((size_t)24 << 20));
    u16* ctx   = (u16*)(ws + ((size_t)32 << 20));
    float* x2  = (float*)(ws + ((size_t)40 << 20));
    u16* yln   = (u16*)(ws + ((size_t)56 << 20));
    u16* hbuf  = (u16*)(ws + ((size_t)64 << 20));
    u16* WqkvT = (u16*)(ws + ((size_t)80 << 20));
    u16* WoT   = (u16*)(ws + ((size_t)80 << 20) + 393216);
    u16* W1T   = (u16*)(ws + ((size_t)80 << 20) + 393216 + 131072);
    u16* W2T   = (u16*)(ws + ((size_t)80 << 20) + 393216 + 131072 + 262144);

    prep_kernel<<<2048, 256, 0, stream>>>(Wq, Wk, Wv, Wo, W1, W2, WqkvT, WoT, W1T, W2T);
    ln_kernel<<<4096, 256, 0, stream>>>(tokens, n1w, n1b, xln);
    gemm_bt<0, 256><<<dim3(6, 128), 256, 0, stream>>>(xln, WqkvT, bq, bk, bv,
                                                      nullptr, nullptr, qb, kb, vT);
    attn_kernel<<<512, 256, 0, stream>>>(qb, kb, vT, importance, ctx);
    gemm_bt<1, 256><<<dim3(2, 128), 256, 0, stream>>>(ctx, WoT, bo, nullptr, nullptr,
                                                      tokens, x2, nullptr, nullptr, nullptr);
    ln_kernel<<<4096, 256, 0, stream>>>(x2, n2w, n2b, yln);
    gemm_bt<2, 256><<<dim3(4, 128), 256, 0, stream>>>(yln, W1T, b1, nullptr, nullptr,
                                                      nullptr, nullptr, hbuf, nullptr, nullptr);
    gemm_bt<3, 512><<<dim3(2, 128), 256, 0, stream>>>(hbuf, W2T, b2, nullptr, nullptr,
                                                      x2, out, nullptr, nullptr, nullptr);
}

// Round 3
// 225.760 us; speedup vs baseline: 1.5864x; 1.2050x over previous
//
#include <hip/hip_runtime.h>

#define Bb 4
#define Nn 4096
#define Dd 256
#define Hh 4
#define HDd 64
#define FFf 512
#define MT 16384  // B*N

typedef __attribute__((ext_vector_type(8))) short short8;
typedef __attribute__((ext_vector_type(4))) float f32x4;
typedef __attribute__((ext_vector_type(16))) float f32x16;
typedef unsigned short u16;
typedef unsigned int u32;
typedef __attribute__((ext_vector_type(4))) u32 u32x4;

typedef __attribute__((address_space(1))) const void glb_src;
typedef __attribute__((address_space(3))) void lds_dst;

__device__ __forceinline__ void gload_lds16(const void* g, void* l) {
    __builtin_amdgcn_global_load_lds((glb_src*)g, (lds_dst*)l, 16, 0, 0);
}

__device__ __forceinline__ u16 f2bf(float f) {
    union { float f; u32 i; } v; v.f = f;
    u32 r = v.i + 0x7FFFu + ((v.i >> 16) & 1u);
    return (u16)(r >> 16);
}

__device__ __forceinline__ short8 ld8(const u16* p) {
    return *(const short8*)p;
}

// v_permlane32_swap: a' = [a.lo, b.lo], b' = [a.hi, b.hi]
__device__ __forceinline__ void pl32swap(u32& a, u32& b) {
    asm("v_permlane32_swap_b32 %0, %1" : "+v"(a), "+v"(b));
}
__device__ __forceinline__ float xhalf_max(float x) {
    u32 a = __float_as_uint(x), b = a;
    pl32swap(a, b);
    return fmaxf(__uint_as_float(a), __uint_as_float(b));
}
__device__ __forceinline__ u32 cvtpk(float lo, float hi) {
    u32 r;
    asm("v_cvt_pk_bf16_f32 %0, %1, %2" : "=v"(r) : "v"(lo), "v"(hi));
    return r;
}
__device__ __forceinline__ float fexp2(float x) {
    float r;
    asm("v_exp_f32 %0, %1" : "=v"(r) : "v"(x));
    return r;
}
__device__ __forceinline__ float max3f(float a, float b, float c) {
    float r;
    asm("v_max3_f32 %0, %1, %2, %3" : "=v"(r) : "v"(a), "v"(b), "v"(c));
    return r;
}

#define QSCALE 0.18033610062f  /* 0.125 * log2(e) */
#define LOG2E  1.44269504089f

// ---------------- weight prep: transpose + bf16 cast + imp pack ----------------
__global__ __launch_bounds__(256) void prep_kernel(
        const float* __restrict__ Wq, const float* __restrict__ Wk,
        const float* __restrict__ Wv, const float* __restrict__ Wo,
        const float* __restrict__ W1, const float* __restrict__ W2,
        const float* __restrict__ imp,
        u16* __restrict__ WqkvT, u16* __restrict__ WoT,
        u16* __restrict__ W1T, u16* __restrict__ W2T,
        u32* __restrict__ impPk) {
    int e = blockIdx.x * 256 + threadIdx.x;
    if (e < 196608) {                    // 768*256
        int c = e >> 8, k = e & 255;
        int mat = c >> 8;                // 0=q,1=k,2=v
        int cc = c & 255;
        const float* W = (mat == 0) ? Wq : ((mat == 1) ? Wk : Wv);
        WqkvT[(size_t)c * 256 + k] = f2bf(W[k * 256 + cc]);
    } else if (e < 262144) {
        int i = e - 196608; int n = i >> 8, k = i & 255;
        WoT[n * 256 + k] = f2bf(Wo[k * 256 + n]);
    } else if (e < 393216) {
        int i = e - 262144; int n = i >> 8, k = i & 255;
        W1T[n * 256 + k] = f2bf(W1[k * 512 + n]);
    } else if (e < 524288) {
        int i = e - 393216; int n = i >> 9, k = i & 511;
        W2T[n * 512 + k] = f2bf(W2[k * 256 + n]);
    } else {
        int i = e - 524288;              // 0..16383 = B*N importance entries
        float ivs = imp[i] * LOG2E;
        u16 ih = f2bf(ivs);
        float rem = ivs - __uint_as_float(((u32)ih) << 16);
        u16 il = f2bf(rem);
        impPk[i] = ((u32)il << 16) | ih;
    }
}

// ---------------- LayerNorm ----------------
__global__ __launch_bounds__(256) void ln_kernel(const float* __restrict__ x,
        const float* __restrict__ w, const float* __restrict__ bia,
        u16* __restrict__ out) {
    int lane = threadIdx.x & 63;
    int row = blockIdx.x * 4 + (threadIdx.x >> 6);
    const float* xr = x + (size_t)row * Dd;
    float4 v = *(const float4*)(xr + lane * 4);
    float s = v.x + v.y + v.z + v.w;
    float s2 = v.x * v.x + v.y * v.y + v.z * v.z + v.w * v.w;
    #pragma unroll
    for (int off = 1; off < 64; off <<= 1) {
        s  += __shfl_xor(s, off);
        s2 += __shfl_xor(s2, off);
    }
    float mu = s * (1.0f / Dd);
    float var = s2 * (1.0f / Dd) - mu * mu;
    float rstd = rsqrtf(var + 1e-5f);
    float4 wv = *(const float4*)(w + lane * 4);
    float4 bv = *(const float4*)(bia + lane * 4);
    ushort4 ov;
    ov.x = f2bf((v.x - mu) * rstd * wv.x + bv.x);
    ov.y = f2bf((v.y - mu) * rstd * wv.y + bv.y);
    ov.z = f2bf((v.z - mu) * rstd * wv.z + bv.z);
    ov.w = f2bf((v.w - mu) * rstd * wv.w + bv.w);
    *(ushort4*)(out + (size_t)row * Dd + lane * 4) = ov;
}

// ---------------- GEMM: A[M,K] bf16 x BT[N,K] bf16 -> epilogue ----------------
template<int MODE, int KD>
__global__ __launch_bounds__(256) void gemm_bt(
        const u16* __restrict__ A, const u16* __restrict__ BT,
        const float* __restrict__ bias0, const float* __restrict__ bias1,
        const float* __restrict__ bias2,
        const float* __restrict__ resid, float* __restrict__ outf,
        u16* __restrict__ o0, u16* __restrict__ o1, u16* __restrict__ o2) {
    __shared__ u16 Asl[128 * 32];
    __shared__ u16 Bsl[128 * 32];
    int lane = threadIdx.x & 63;
    int wv = threadIdx.x >> 6;
    int wm = wv >> 1, wn = wv & 1;
    int m0 = blockIdx.y * 128, n0 = blockIdx.x * 128;
    f32x4 zz; zz[0] = 0.f; zz[1] = 0.f; zz[2] = 0.f; zz[3] = 0.f;
    f32x4 acc[4][4];
    #pragma unroll
    for (int i = 0; i < 4; ++i)
        #pragma unroll
        for (int j = 0; j < 4; ++j) acc[i][j] = zz;

    for (int kt = 0; kt < KD; kt += 32) {
        __syncthreads();
        #pragma unroll
        for (int i = 0; i < 2; ++i) {
            int chunk = threadIdx.x + i * 256;
            int row = chunk >> 2, c16 = chunk & 3;
            int lofs = row * 32 + ((c16 * 8) ^ ((row & 3) * 8));
            *(uint4*)(Asl + lofs) = *(const uint4*)(A + (size_t)(m0 + row) * KD + kt + c16 * 8);
            *(uint4*)(Bsl + lofs) = *(const uint4*)(BT + (size_t)(n0 + row) * KD + kt + c16 * 8);
        }
        __syncthreads();
        short8 af[4], bfr[4];
        #pragma unroll
        for (int t = 0; t < 4; ++t) {
            int arow = wm * 64 + t * 16 + (lane & 15);
            af[t]  = ld8(Asl + arow * 32 + (((lane >> 4) * 8) ^ ((arow & 3) * 8)));
            int brow = wn * 64 + t * 16 + (lane & 15);
            bfr[t] = ld8(Bsl + brow * 32 + (((lane >> 4) * 8) ^ ((brow & 3) * 8)));
        }
        #pragma unroll
        for (int mt = 0; mt < 4; ++mt)
            #pragma unroll
            for (int nt = 0; nt < 4; ++nt)
                acc[mt][nt] = __builtin_amdgcn_mfma_f32_16x16x32_bf16(af[mt], bfr[nt], acc[mt][nt], 0, 0, 0);
    }

    #pragma unroll
    for (int mt = 0; mt < 4; ++mt) {
        #pragma unroll
        for (int nt = 0; nt < 4; ++nt) {
            #pragma unroll
            for (int r = 0; r < 4; ++r) {
                int row = m0 + wm * 64 + mt * 16 + (lane >> 4) * 4 + r;
                int col = n0 + wn * 64 + nt * 16 + (lane & 15);
                float v = acc[mt][nt][r];
                if (MODE == 0) {
                    int mat = col >> 8;
                    int cc = col & 255;
                    int hh = cc >> 6, dd = cc & 63;
                    int bbi = row >> 12, nni = row & 4095;
                    int bh = bbi * Hh + hh;
                    // q pre-scaled by 0.125*log2(e) for exp2-domain flash attention
                    if (mat == 0)      o0[((size_t)bh * Nn + nni) * HDd + dd] = f2bf((v + bias0[cc]) * QSCALE);
                    else if (mat == 1) o1[((size_t)bh * Nn + nni) * HDd + dd] = f2bf(v + bias1[cc]);
                    else               o2[((size_t)bh * HDd + dd) * Nn + nni] = f2bf(v + bias2[cc]);
                } else if (MODE == 1) {
                    outf[(size_t)row * Dd + col] = resid[(size_t)row * Dd + col] + v + bias0[col];
                } else if (MODE == 2) {
                    float xg = v + bias0[col];
                    float g = 0.5f * xg * (1.0f + erff(xg * 0.70710678118654752f));
                    o0[(size_t)row * FFf + col] = f2bf(g);
                } else {
                    outf[(size_t)row * Dd + col] = resid[(size_t)row * Dd + col] + v + bias0[col];
                }
            }
        }
    }
}

// ---------------- Flash attention, swapped-operand 32x32x16 ----------------
// Double-buffered K/V LDS staged via global_load_lds (pre-swizzled source,
// linear dest, XOR-swz read). Softmax in-register; l accumulated via all-ones
// MFMA; raw v_exp_f32; packed importance prefetched one tile ahead.
__global__ __launch_bounds__(256) void attn_kernel(
        const u16* __restrict__ Qb, const u16* __restrict__ Kb,
        const u16* __restrict__ VTb, const u32* __restrict__ impPk,
        u16* __restrict__ ctxOut) {
    __shared__ u16 Klds[2][64 * 64];
    __shared__ u16 Vlds[2][64 * 64];
    __shared__ float Clds[4][32 * 64];
    int lane = threadIdx.x & 63;
    int wv = threadIdx.x >> 6;
    int bh = blockIdx.x >> 5;
    int qt = blockIdx.x & 31;
    int bbi = bh >> 2, hh = bh & 3;
    int qrow0 = qt * 128 + wv * 32;
    int q = lane & 31;
    int hf = lane >> 5;

    // Q B-frags (hoisted)
    short8 qf[4];
    #pragma unroll
    for (int ks = 0; ks < 4; ++ks)
        qf[ks] = ld8(Qb + ((size_t)bh * Nn + qrow0 + q) * HDd + ks * 16 + hf * 8);

    // B-frag with ones at k=0,1 (for importance augmentation)
    short8 onef = (short8)0;
    if (hf == 0) { onef[0] = (short)0x3F80; onef[1] = (short)0x3F80; }
    // all-ones A-frag (for l accumulation)
    short8 aone;
    #pragma unroll
    for (int j = 0; j < 8; ++j) aone[j] = (short)0x3F80;

    // staging geometry: lane l covers LDS row base+(l>>3), 16B slot l&7;
    // source pre-swizzled so read-side XOR finds the right data
    int sr = lane >> 3;
    int sc = lane & 7;
    int swz = (sc ^ sr) * 8;
    const u16* kp = Kb + ((size_t)bh * Nn + wv * 16 + sr) * HDd + swz;
    const u16* vp = VTb + ((size_t)bh * HDd + wv * 16 + sr) * Nn + swz;
    size_t ib = (size_t)bbi * Nn;

    // prologue: stage tile 0 into buf 0
    gload_lds16(kp,           (char*)Klds[0] + wv * 2048);
    gload_lds16(kp + 8 * HDd, (char*)Klds[0] + wv * 2048 + 1024);
    gload_lds16(vp,           (char*)Vlds[0] + wv * 2048);
    gload_lds16(vp + 8 * Nn,  (char*)Vlds[0] + wv * 2048 + 1024);
    kp += 64 * HDd; vp += 64;
    u32 npk0 = impPk[ib + q], npk1 = impPk[ib + 32 + q];

    f32x16 ctx[2], lacc;
    #pragma unroll
    for (int r = 0; r < 16; ++r) { ctx[0][r] = 0.f; ctx[1][r] = 0.f; lacc[r] = 0.f; }
    float m = -__builtin_inff();

    int cur = 0;
    for (int kt = 0; kt < Nn; kt += 64) {
        __syncthreads();   // drains vmcnt: buf[cur] ready; buf[cur^1] free
        u32 pk0 = npk0, pk1 = npk1;
        if (kt + 64 < Nn) {
            gload_lds16(kp,           (char*)Klds[cur ^ 1] + wv * 2048);
            gload_lds16(kp + 8 * HDd, (char*)Klds[cur ^ 1] + wv * 2048 + 1024);
            gload_lds16(vp,           (char*)Vlds[cur ^ 1] + wv * 2048);
            gload_lds16(vp + 8 * Nn,  (char*)Vlds[cur ^ 1] + wv * 2048 + 1024);
            kp += 64 * HDd; vp += 64;
            npk0 = impPk[ib + kt + 64 + q];
            npk1 = impPk[ib + kt + 96 + q];
        }
        const u16* Kc = Klds[cur];
        const u16* Vc = Vlds[cur];

        #pragma unroll
        for (int st = 0; st < 2; ++st) {
            int krow = st * 32 + q;
            f32x16 s;
            #pragma unroll
            for (int r = 0; r < 16; ++r) s[r] = 0.f;
            __builtin_amdgcn_s_setprio(1);
            #pragma unroll
            for (int ks = 0; ks < 4; ++ks) {
                short8 kf = ld8(Kc + krow * 64 + (((ks * 2 + hf) ^ (krow & 7)) * 8));
                s = __builtin_amdgcn_mfma_f32_32x32x16_bf16(kf, qf[ks], s, 0, 0, 0);
            }
            // augmented slice adds imp[key]*log2e (prepacked hi/lo bf16)
            u32 pk = st ? pk1 : pk0;
            short8 af = (short8)0;
            if (hf == 0) { af[0] = (short)(pk & 0xFFFFu); af[1] = (short)(pk >> 16); }
            s = __builtin_amdgcn_mfma_f32_32x32x16_bf16(af, onef, s, 0, 0, 0);
            __builtin_amdgcn_s_setprio(0);

            // ---- in-register online softmax (exp2 domain) ----
            float g0 = max3f(s[0], s[1], s[2]);
            float g1 = max3f(s[3], s[4], s[5]);
            float g2 = max3f(s[6], s[7], s[8]);
            float g3 = max3f(s[9], s[10], s[11]);
            float g4 = max3f(s[12], s[13], s[14]);
            float h0 = max3f(g0, g1, g2);
            float h1 = max3f(g3, g4, s[15]);
            float tm = xhalf_max(fmaxf(h0, h1));
            bool nore = __all(tm <= m + 8.0f);
            if (!nore) {
                float nm = fmaxf(m, tm);
                float al = fexp2(m - nm);
                lacc[0] *= al;
                #pragma unroll
                for (int r = 0; r < 16; ++r) { ctx[0][r] *= al; ctx[1][r] *= al; }
                m = nm;
            }
            #pragma unroll
            for (int r = 0; r < 16; ++r) s[r] = fexp2(s[r] - m);

            // ---- P -> bf16 B-frags in-register ----
            u32 w[8];
            #pragma unroll
            for (int j = 0; j < 8; ++j) w[j] = cvtpk(s[2 * j], s[2 * j + 1]);
            pl32swap(w[0], w[2]); pl32swap(w[1], w[3]);
            pl32swap(w[4], w[6]); pl32swap(w[5], w[7]);
            u32x4 t0; t0[0] = w[0]; t0[1] = w[1]; t0[2] = w[2]; t0[3] = w[3];
            u32x4 t1; t1[0] = w[4]; t1[1] = w[5]; t1[2] = w[6]; t1[3] = w[7];
            short8 pf0 = __builtin_bit_cast(short8, t0);
            short8 pf1 = __builtin_bit_cast(short8, t1);

            // ---- PV + l-accumulation (all-ones A row-sums P) ----
            __builtin_amdgcn_s_setprio(1);
            lacc = __builtin_amdgcn_mfma_f32_32x32x16_bf16(aone, pf0, lacc, 0, 0, 0);
            lacc = __builtin_amdgcn_mfma_f32_32x32x16_bf16(aone, pf1, lacc, 0, 0, 0);
            #pragma unroll
            for (int dt = 0; dt < 2; ++dt) {
                int vrow = dt * 32 + q;
                short8 vf0 = ld8(Vc + vrow * 64 + (((st * 4 + hf) ^ (vrow & 7)) * 8));
                ctx[dt] = __builtin_amdgcn_mfma_f32_32x32x16_bf16(vf0, pf0, ctx[dt], 0, 0, 0);
                short8 vf1 = ld8(Vc + vrow * 64 + (((st * 4 + 2 + hf) ^ (vrow & 7)) * 8));
                ctx[dt] = __builtin_amdgcn_mfma_f32_32x32x16_bf16(vf1, pf1, ctx[dt], 0, 0, 0);
            }
            __builtin_amdgcn_s_setprio(0);
        }
        cur ^= 1;
    }

    // ---- epilogue: normalize, transpose via LDS, coalesced store ----
    float inv = 1.0f / lacc[0];
    #pragma unroll
    for (int dt = 0; dt < 2; ++dt) {
        #pragma unroll
        for (int r = 0; r < 16; ++r) {
            int d = dt * 32 + (r & 3) + 8 * (r >> 2) + 4 * hf;
            Clds[wv][q * 64 + (d ^ ((q & 7) << 2))] = ctx[dt][r] * inv;
        }
    }
    u16* op = ctxOut + ((size_t)bbi * Nn + qrow0 + q) * Dd + hh * HDd + hf * 32;
    #pragma unroll
    for (int gp = 0; gp < 4; ++gp) {
        int gi0 = hf * 8 + gp * 2, gi1 = gi0 + 1;
        int g0 = (gi0 & 8) | ((gi0 & 7) ^ (q & 7));
        int g1 = (gi1 & 8) | ((gi1 & 7) ^ (q & 7));
        float4 v0 = *(const float4*)(&Clds[wv][q * 64 + g0 * 4]);
        float4 v1 = *(const float4*)(&Clds[wv][q * 64 + g1 * 4]);
        uint4 pkv;
        pkv.x = cvtpk(v0.x, v0.y); pkv.y = cvtpk(v0.z, v0.w);
        pkv.z = cvtpk(v1.x, v1.y); pkv.w = cvtpk(v1.z, v1.w);
        *(uint4*)(op + gp * 8) = pkv;
    }
}

extern "C" void kernel_launch(void* const* d_in, const int* in_sizes, int n_in,
                              void* d_out, int out_size, void* d_ws, size_t ws_size,
                              hipStream_t stream) {
    (void)in_sizes; (void)n_in; (void)out_size; (void)ws_size;
    const float* tokens     = (const float*)d_in[0];
    const float* importance = (const float*)d_in[1];
    const float* n1w = (const float*)d_in[2];
    const float* n1b = (const float*)d_in[3];
    const float* Wq  = (const float*)d_in[4];
    const float* bq  = (const float*)d_in[5];
    const float* Wk  = (const float*)d_in[6];
    const float* bk  = (const float*)d_in[7];
    const float* Wv  = (const float*)d_in[8];
    const float* bv  = (const float*)d_in[9];
    const float* Wo  = (const float*)d_in[10];
    const float* bo  = (const float*)d_in[11];
    const float* n2w = (const float*)d_in[12];
    const float* n2b = (const float*)d_in[13];
    const float* W1  = (const float*)d_in[14];
    const float* b1  = (const float*)d_in[15];
    const float* W2  = (const float*)d_in[16];
    const float* b2  = (const float*)d_in[17];
    float* out = (float*)d_out;

    char* ws = (char*)d_ws;
    u16* xln   = (u16*)(ws);
    u16* qb    = (u16*)(ws + ((size_t)8 << 20));
    u16* kb    = (u16*)(ws + ((size_t)16 << 20));
    u16* vT    = (u16*)(ws + ((size_t)24 << 20));
    u16* ctx   = (u16*)(ws + ((size_t)32 << 20));
    float* x2  = (float*)(ws + ((size_t)40 << 20));
    u16* yln   = (u16*)(ws + ((size_t)56 << 20));
    u16* hbuf  = (u16*)(ws + ((size_t)64 << 20));
    u16* WqkvT = (u16*)(ws + ((size_t)80 << 20));
    u16* WoT   = (u16*)(ws + ((size_t)80 << 20) + 393216);
    u16* W1T   = (u16*)(ws + ((size_t)80 << 20) + 393216 + 131072);
    u16* W2T   = (u16*)(ws + ((size_t)80 << 20) + 393216 + 131072 + 262144);
    u32* impPk = (u32*)(ws + ((size_t)80 << 20) + 393216 + 131072 + 262144 + 262144);

    prep_kernel<<<2112, 256, 0, stream>>>(Wq, Wk, Wv, Wo, W1, W2, importance,
                                          WqkvT, WoT, W1T, W2T, impPk);
    ln_kernel<<<4096, 256, 0, stream>>>(tokens, n1w, n1b, xln);
    gemm_bt<0, 256><<<dim3(6, 128), 256, 0, stream>>>(xln, WqkvT, bq, bk, bv,
                                                      nullptr, nullptr, qb, kb, vT);
    attn_kernel<<<512, 256, 0, stream>>>(qb, kb, vT, impPk, ctx);
    gemm_bt<1, 256><<<dim3(2, 128), 256, 0, stream>>>(ctx, WoT, bo, nullptr, nullptr,
                                                      tokens, x2, nullptr, nullptr, nullptr);
    ln_kernel<<<4096, 256, 0, stream>>>(x2, n2w, n2b, yln);
    gemm_bt<2, 256><<<dim3(4, 128), 256, 0, stream>>>(yln, W1T, b1, nullptr, nullptr,
                                                      nullptr, nullptr, hbuf, nullptr, nullptr);
    gemm_bt<3, 512><<<dim3(2, 128), 256, 0, stream>>>(hbuf, W2T, b2, nullptr, nullptr,
                                                      x2, out, nullptr, nullptr, nullptr);
}

// Round 5
// 202.177 us; speedup vs baseline: 1.7714x; 1.1166x over previous
//
#include <hip/hip_runtime.h>

#define Bb 4
#define Nn 4096
#define Dd 256
#define Hh 4
#define HDd 64
#define FFf 512
#define MT 16384  // B*N

typedef __attribute__((ext_vector_type(8))) short short8;
typedef __attribute__((ext_vector_type(4))) float f32x4;
typedef __attribute__((ext_vector_type(16))) float f32x16;
typedef unsigned short u16;
typedef unsigned int u32;
typedef __attribute__((ext_vector_type(4))) u32 u32x4;

typedef __attribute__((address_space(1))) const void glb_src;
typedef __attribute__((address_space(3))) void lds_dst;

__device__ __forceinline__ void gload_lds16(const void* g, void* l) {
    __builtin_amdgcn_global_load_lds((glb_src*)g, (lds_dst*)l, 16, 0, 0);
}

__device__ __forceinline__ u16 f2bf(float f) {
    union { float f; u32 i; } v; v.f = f;
    u32 r = v.i + 0x7FFFu + ((v.i >> 16) & 1u);
    return (u16)(r >> 16);
}

__device__ __forceinline__ short8 ld8(const u16* p) {
    return *(const short8*)p;
}

// v_permlane32_swap: a' = [a.lo, b.lo], b' = [a.hi, b.hi]
__device__ __forceinline__ void pl32swap(u32& a, u32& b) {
    asm("v_permlane32_swap_b32 %0, %1" : "+v"(a), "+v"(b));
}
__device__ __forceinline__ float xhalf_max(float x) {
    u32 a = __float_as_uint(x), b = a;
    pl32swap(a, b);
    return fmaxf(__uint_as_float(a), __uint_as_float(b));
}
__device__ __forceinline__ u32 cvtpk(float lo, float hi) {
    u32 r;
    asm("v_cvt_pk_bf16_f32 %0, %1, %2" : "=v"(r) : "v"(lo), "v"(hi));
    return r;
}
__device__ __forceinline__ float fexp2(float x) {
    float r;
    asm("v_exp_f32 %0, %1" : "=v"(r) : "v"(x));
    return r;
}
__device__ __forceinline__ float max3f(float a, float b, float c) {
    float r;
    asm("v_max3_f32 %0, %1, %2, %3" : "=v"(r) : "v"(a), "v"(b), "v"(c));
    return r;
}

#define QSCALE 0.18033610062f  /* 0.125 * log2(e) */
#define LOG2E  1.44269504089f

// ---------------- weight prep: transpose + bf16 cast + imp pack ----------------
__global__ __launch_bounds__(256) void prep_kernel(
        const float* __restrict__ Wq, const float* __restrict__ Wk,
        const float* __restrict__ Wv, const float* __restrict__ Wo,
        const float* __restrict__ W1, const float* __restrict__ W2,
        const float* __restrict__ imp,
        u16* __restrict__ WqkvT, u16* __restrict__ WoT,
        u16* __restrict__ W1T, u16* __restrict__ W2T,
        u32* __restrict__ impPk) {
    int e = blockIdx.x * 256 + threadIdx.x;
    if (e < 196608) {                    // 768*256
        int c = e >> 8, k = e & 255;
        int mat = c >> 8;                // 0=q,1=k,2=v
        int cc = c & 255;
        const float* W = (mat == 0) ? Wq : ((mat == 1) ? Wk : Wv);
        WqkvT[(size_t)c * 256 + k] = f2bf(W[k * 256 + cc]);
    } else if (e < 262144) {
        int i = e - 196608; int n = i >> 8, k = i & 255;
        WoT[n * 256 + k] = f2bf(Wo[k * 256 + n]);
    } else if (e < 393216) {
        int i = e - 262144; int n = i >> 8, k = i & 255;
        W1T[n * 256 + k] = f2bf(W1[k * 512 + n]);
    } else if (e < 524288) {
        int i = e - 393216; int n = i >> 9, k = i & 511;
        W2T[n * 512 + k] = f2bf(W2[k * 256 + n]);
    } else {
        int i = e - 524288;              // 0..16383 = B*N importance entries
        float ivs = imp[i] * LOG2E;
        u16 ih = f2bf(ivs);
        float rem = ivs - __uint_as_float(((u32)ih) << 16);
        u16 il = f2bf(rem);
        impPk[i] = ((u32)il << 16) | ih;
    }
}

// ---------------- LayerNorm ----------------
__global__ __launch_bounds__(256) void ln_kernel(const float* __restrict__ x,
        const float* __restrict__ w, const float* __restrict__ bia,
        u16* __restrict__ out) {
    int lane = threadIdx.x & 63;
    int row = blockIdx.x * 4 + (threadIdx.x >> 6);
    const float* xr = x + (size_t)row * Dd;
    float4 v = *(const float4*)(xr + lane * 4);
    float s = v.x + v.y + v.z + v.w;
    float s2 = v.x * v.x + v.y * v.y + v.z * v.z + v.w * v.w;
    #pragma unroll
    for (int off = 1; off < 64; off <<= 1) {
        s  += __shfl_xor(s, off);
        s2 += __shfl_xor(s2, off);
    }
    float mu = s * (1.0f / Dd);
    float var = s2 * (1.0f / Dd) - mu * mu;
    float rstd = rsqrtf(var + 1e-5f);
    float4 wv = *(const float4*)(w + lane * 4);
    float4 bv = *(const float4*)(bia + lane * 4);
    ushort4 ov;
    ov.x = f2bf((v.x - mu) * rstd * wv.x + bv.x);
    ov.y = f2bf((v.y - mu) * rstd * wv.y + bv.y);
    ov.z = f2bf((v.z - mu) * rstd * wv.z + bv.z);
    ov.w = f2bf((v.w - mu) * rstd * wv.w + bv.w);
    *(ushort4*)(out + (size_t)row * Dd + lane * 4) = ov;
}

// ---------------- GEMM: A[M,K] bf16 x BT[N,K] bf16 -> epilogue ----------------
// Staging via global_load_lds w16: linear LDS dest, inverse-swizzled source.
template<int MODE, int KD>
__global__ __launch_bounds__(256) void gemm_bt(
        const u16* __restrict__ A, const u16* __restrict__ BT,
        const float* __restrict__ bias0, const float* __restrict__ bias1,
        const float* __restrict__ bias2,
        const float* __restrict__ resid, float* __restrict__ outf,
        u16* __restrict__ o0, u16* __restrict__ o1, u16* __restrict__ o2) {
    __shared__ u16 Asl[128 * 32];
    __shared__ u16 Bsl[128 * 32];
    int lane = threadIdx.x & 63;
    int wv = threadIdx.x >> 6;
    int wm = wv >> 1, wn = wv & 1;
    int m0 = blockIdx.y * 128, n0 = blockIdx.x * 128;
    f32x4 zz; zz[0] = 0.f; zz[1] = 0.f; zz[2] = 0.f; zz[3] = 0.f;
    f32x4 acc[4][4];
    #pragma unroll
    for (int i = 0; i < 4; ++i)
        #pragma unroll
        for (int j = 0; j < 4; ++j) acc[i][j] = zz;

    for (int kt = 0; kt < KD; kt += 32) {
        __syncthreads();
        #pragma unroll
        for (int i = 0; i < 2; ++i) {
            int chunk = threadIdx.x + i * 256;
            int row = chunk >> 2, c16 = chunk & 3;
            int srcc = (c16 ^ (row & 3)) * 8;     // inverse swizzle on source
            char* adst = (char*)Asl + wv * 1024 + i * 4096;  // wave-uniform base
            char* bdst = (char*)Bsl + wv * 1024 + i * 4096;
            gload_lds16(A  + (size_t)(m0 + row) * KD + kt + srcc, adst);
            gload_lds16(BT + (size_t)(n0 + row) * KD + kt + srcc, bdst);
        }
        __syncthreads();
        short8 af[4], bfr[4];
        #pragma unroll
        for (int t = 0; t < 4; ++t) {
            int arow = wm * 64 + t * 16 + (lane & 15);
            af[t]  = ld8(Asl + arow * 32 + (((lane >> 4) * 8) ^ ((arow & 3) * 8)));
            int brow = wn * 64 + t * 16 + (lane & 15);
            bfr[t] = ld8(Bsl + brow * 32 + (((lane >> 4) * 8) ^ ((brow & 3) * 8)));
        }
        #pragma unroll
        for (int mt = 0; mt < 4; ++mt)
            #pragma unroll
            for (int nt = 0; nt < 4; ++nt)
                acc[mt][nt] = __builtin_amdgcn_mfma_f32_16x16x32_bf16(af[mt], bfr[nt], acc[mt][nt], 0, 0, 0);
    }

    #pragma unroll
    for (int mt = 0; mt < 4; ++mt) {
        #pragma unroll
        for (int nt = 0; nt < 4; ++nt) {
            #pragma unroll
            for (int r = 0; r < 4; ++r) {
                int row = m0 + wm * 64 + mt * 16 + (lane >> 4) * 4 + r;
                int col = n0 + wn * 64 + nt * 16 + (lane & 15);
                float v = acc[mt][nt][r];
                if (MODE == 0) {
                    int mat = col >> 8;
                    int cc = col & 255;
                    int hh = cc >> 6, dd = cc & 63;
                    int bbi = row >> 12, nni = row & 4095;
                    int bh = bbi * Hh + hh;
                    // q pre-scaled by 0.125*log2(e) for exp2-domain flash attention
                    if (mat == 0)      o0[((size_t)bh * Nn + nni) * HDd + dd] = f2bf((v + bias0[cc]) * QSCALE);
                    else if (mat == 1) o1[((size_t)bh * Nn + nni) * HDd + dd] = f2bf(v + bias1[cc]);
                    else               o2[((size_t)bh * HDd + dd) * Nn + nni] = f2bf(v + bias2[cc]);
                } else if (MODE == 1) {
                    outf[(size_t)row * Dd + col] = resid[(size_t)row * Dd + col] + v + bias0[col];
                } else if (MODE == 2) {
                    float xg = v + bias0[col];
                    float g = 0.5f * xg * (1.0f + erff(xg * 0.70710678118654752f));
                    o0[(size_t)row * FFf + col] = f2bf(g);
                } else {
                    outf[(size_t)row * Dd + col] = resid[(size_t)row * Dd + col] + v + bias0[col];
                }
            }
        }
    }
}

// ---------------- Flash attention, KV-split x2, swapped-operand 32x32x16 ----------------
// grid: 2 halves x 16 bh x 32 q-tiles(128). 4 waves x 32 q-rows. Each block
// processes 2048 keys; writes unnormalized ctx^T partials (bf16) + m,l (f32).
__global__ __launch_bounds__(256, 4) void attn_kernel(
        const u16* __restrict__ Qb, const u16* __restrict__ Kb,
        const u16* __restrict__ VTb, const u32* __restrict__ impPk,
        u16* __restrict__ pc, float* __restrict__ pm, float* __restrict__ pl) {
    __shared__ u16 Klds[2][64 * 64];
    __shared__ u16 Vlds[2][64 * 64];
    int lane = threadIdx.x & 63;
    int wv = threadIdx.x >> 6;
    int kvh = blockIdx.x >> 9;
    int bh = (blockIdx.x >> 5) & 15;
    int qt = blockIdx.x & 31;
    int bbi = bh >> 2;
    int qrow0 = qt * 128 + wv * 32;
    int q = lane & 31;
    int hf = lane >> 5;
    int key0 = kvh * 2048;

    // Q B-frags (hoisted)
    short8 qf[4];
    #pragma unroll
    for (int ks = 0; ks < 4; ++ks)
        qf[ks] = ld8(Qb + ((size_t)bh * Nn + qrow0 + q) * HDd + ks * 16 + hf * 8);

    // B-frag with ones at k=0,1 (importance augmentation)
    short8 onef = (short8)0;
    if (hf == 0) { onef[0] = (short)0x3F80; onef[1] = (short)0x3F80; }
    // all-ones A-frag (l accumulation via MFMA row-sum)
    short8 aone;
    #pragma unroll
    for (int j = 0; j < 8; ++j) aone[j] = (short)0x3F80;

    // staging: lane covers LDS row base+(l>>3), slot l&7; source pre-swizzled
    int sr = lane >> 3;
    int sc = lane & 7;
    int swz = (sc ^ sr) * 8;
    const u16* kp = Kb + ((size_t)bh * Nn + key0 + wv * 16 + sr) * HDd + swz;
    const u16* vp = VTb + ((size_t)bh * HDd + wv * 16 + sr) * Nn + key0 + swz;
    size_t ib = (size_t)bbi * Nn;

    gload_lds16(kp,           (char*)Klds[0] + wv * 2048);
    gload_lds16(kp + 8 * HDd, (char*)Klds[0] + wv * 2048 + 1024);
    gload_lds16(vp,           (char*)Vlds[0] + wv * 2048);
    gload_lds16(vp + 8 * Nn,  (char*)Vlds[0] + wv * 2048 + 1024);
    kp += 64 * HDd; vp += 64;
    u32 npk0 = impPk[ib + key0 + q], npk1 = impPk[ib + key0 + 32 + q];

    f32x16 ctx[2], lacc;
    #pragma unroll
    for (int r = 0; r < 16; ++r) { ctx[0][r] = 0.f; ctx[1][r] = 0.f; lacc[r] = 0.f; }
    float m = -__builtin_inff();

    int cur = 0;
    for (int t = 0; t < 32; ++t) {
        __syncthreads();   // buf[cur] ready; buf[cur^1] free
        u32 pk0 = npk0, pk1 = npk1;
        if (t < 31) {
            gload_lds16(kp,           (char*)Klds[cur ^ 1] + wv * 2048);
            gload_lds16(kp + 8 * HDd, (char*)Klds[cur ^ 1] + wv * 2048 + 1024);
            gload_lds16(vp,           (char*)Vlds[cur ^ 1] + wv * 2048);
            gload_lds16(vp + 8 * Nn,  (char*)Vlds[cur ^ 1] + wv * 2048 + 1024);
            kp += 64 * HDd; vp += 64;
            npk0 = impPk[ib + key0 + t * 64 + 64 + q];
            npk1 = impPk[ib + key0 + t * 64 + 96 + q];
        }
        const u16* Kc = Klds[cur];
        const u16* Vc = Vlds[cur];

        // ---- QK^T both 32-key halves interleaved ----
        f32x16 s0, s1;
        #pragma unroll
        for (int r = 0; r < 16; ++r) { s0[r] = 0.f; s1[r] = 0.f; }
        __builtin_amdgcn_s_setprio(1);
        #pragma unroll
        for (int ks = 0; ks < 4; ++ks) {
            short8 kf0 = ld8(Kc + q * 64 + (((ks * 2 + hf) ^ (q & 7)) * 8));
            short8 kf1 = ld8(Kc + (32 + q) * 64 + (((ks * 2 + hf) ^ (q & 7)) * 8));
            s0 = __builtin_amdgcn_mfma_f32_32x32x16_bf16(kf0, qf[ks], s0, 0, 0, 0);
            s1 = __builtin_amdgcn_mfma_f32_32x32x16_bf16(kf1, qf[ks], s1, 0, 0, 0);
        }
        short8 af0 = (short8)0, af1 = (short8)0;
        if (hf == 0) {
            af0[0] = (short)(pk0 & 0xFFFFu); af0[1] = (short)(pk0 >> 16);
            af1[0] = (short)(pk1 & 0xFFFFu); af1[1] = (short)(pk1 >> 16);
        }
        s0 = __builtin_amdgcn_mfma_f32_32x32x16_bf16(af0, onef, s0, 0, 0, 0);
        s1 = __builtin_amdgcn_mfma_f32_32x32x16_bf16(af1, onef, s1, 0, 0, 0);
        __builtin_amdgcn_s_setprio(0);

        // ---- merged online softmax over 32 scores (exp2 domain) ----
        float a0 = max3f(s0[0], s0[1], s0[2]);
        float a1 = max3f(s0[3], s0[4], s0[5]);
        float a2 = max3f(s0[6], s0[7], s0[8]);
        float a3 = max3f(s0[9], s0[10], s0[11]);
        float a4 = max3f(s0[12], s0[13], s0[14]);
        float b0 = max3f(s1[0], s1[1], s1[2]);
        float b1 = max3f(s1[3], s1[4], s1[5]);
        float b2 = max3f(s1[6], s1[7], s1[8]);
        float b3 = max3f(s1[9], s1[10], s1[11]);
        float b4 = max3f(s1[12], s1[13], s1[14]);
        float c0 = max3f(a0, a1, a2);
        float c1 = max3f(a3, a4, s0[15]);
        float c2 = max3f(b0, b1, b2);
        float c3 = max3f(b3, b4, s1[15]);
        float tm = fmaxf(max3f(c0, c1, c2), c3);
        tm = xhalf_max(tm);
        bool nore = __all(tm <= m + 8.0f);
        if (!nore) {
            float nm = fmaxf(m, tm);
            float al = fexp2(m - nm);
            lacc[0] *= al;
            #pragma unroll
            for (int r = 0; r < 16; ++r) { ctx[0][r] *= al; ctx[1][r] *= al; }
            m = nm;
        }
        #pragma unroll
        for (int r = 0; r < 16; ++r) { s0[r] = fexp2(s0[r] - m); s1[r] = fexp2(s1[r] - m); }

        // ---- P -> bf16 B-frags in-register ----
        u32 w0[8], w1[8];
        #pragma unroll
        for (int j = 0; j < 8; ++j) {
            w0[j] = cvtpk(s0[2 * j], s0[2 * j + 1]);
            w1[j] = cvtpk(s1[2 * j], s1[2 * j + 1]);
        }
        pl32swap(w0[0], w0[2]); pl32swap(w0[1], w0[3]);
        pl32swap(w0[4], w0[6]); pl32swap(w0[5], w0[7]);
        pl32swap(w1[0], w1[2]); pl32swap(w1[1], w1[3]);
        pl32swap(w1[4], w1[6]); pl32swap(w1[5], w1[7]);
        u32x4 t00; t00[0] = w0[0]; t00[1] = w0[1]; t00[2] = w0[2]; t00[3] = w0[3];
        u32x4 t01; t01[0] = w0[4]; t01[1] = w0[5]; t01[2] = w0[6]; t01[3] = w0[7];
        u32x4 t10; t10[0] = w1[0]; t10[1] = w1[1]; t10[2] = w1[2]; t10[3] = w1[3];
        u32x4 t11; t11[0] = w1[4]; t11[1] = w1[5]; t11[2] = w1[6]; t11[3] = w1[7];
        short8 pf00 = __builtin_bit_cast(short8, t00);
        short8 pf01 = __builtin_bit_cast(short8, t01);
        short8 pf10 = __builtin_bit_cast(short8, t10);
        short8 pf11 = __builtin_bit_cast(short8, t11);

        // ---- PV + l-accumulation ----
        __builtin_amdgcn_s_setprio(1);
        lacc = __builtin_amdgcn_mfma_f32_32x32x16_bf16(aone, pf00, lacc, 0, 0, 0);
        lacc = __builtin_amdgcn_mfma_f32_32x32x16_bf16(aone, pf01, lacc, 0, 0, 0);
        lacc = __builtin_amdgcn_mfma_f32_32x32x16_bf16(aone, pf10, lacc, 0, 0, 0);
        lacc = __builtin_amdgcn_mfma_f32_32x32x16_bf16(aone, pf11, lacc, 0, 0, 0);
        #pragma unroll
        for (int dt = 0; dt < 2; ++dt) {
            int vrow = dt * 32 + q;
            const u16* vb = Vc + vrow * 64;
            int sw = vrow & 7;
            short8 vf;
            vf = ld8(vb + (((0 + hf) ^ sw) * 8));
            ctx[dt] = __builtin_amdgcn_mfma_f32_32x32x16_bf16(vf, pf00, ctx[dt], 0, 0, 0);
            vf = ld8(vb + (((2 + hf) ^ sw) * 8));
            ctx[dt] = __builtin_amdgcn_mfma_f32_32x32x16_bf16(vf, pf01, ctx[dt], 0, 0, 0);
            vf = ld8(vb + (((4 + hf) ^ sw) * 8));
            ctx[dt] = __builtin_amdgcn_mfma_f32_32x32x16_bf16(vf, pf10, ctx[dt], 0, 0, 0);
            vf = ld8(vb + (((6 + hf) ^ sw) * 8));
            ctx[dt] = __builtin_amdgcn_mfma_f32_32x32x16_bf16(vf, pf11, ctx[dt], 0, 0, 0);
        }
        __builtin_amdgcn_s_setprio(0);
        cur ^= 1;
    }

    // ---- epilogue: write unnormalized partials ----
    int qg = qrow0 + q;
    if (hf == 0) {
        pm[(size_t)(kvh * 16 + bh) * Nn + qg] = m;
        pl[(size_t)(kvh * 16 + bh) * Nn + qg] = lacc[0];
    }
    #pragma unroll
    for (int dt = 0; dt < 2; ++dt) {
        #pragma unroll
        for (int r = 0; r < 16; ++r) {
            int d = dt * 32 + (r & 3) + 8 * (r >> 2) + 4 * hf;
            pc[((size_t)(kvh * 16 + bh) * 64 + d) * Nn + qg] = f2bf(ctx[dt][r]);
        }
    }
}

// ---------------- merge: combine 2 KV-halves, transpose to ctx layout ----------------
__global__ __launch_bounds__(256) void merge_kernel(
        const u16* __restrict__ pc, const float* __restrict__ pm,
        const float* __restrict__ pl, u16* __restrict__ ctxOut) {
    __shared__ float trans[64][65];
    __shared__ float f0a[64], f1a[64];
    int bh = blockIdx.x >> 6;
    int q0 = (blockIdx.x & 63) * 64;
    int t = threadIdx.x;
    if (t < 64) {
        int qg = q0 + t;
        float m0 = pm[(size_t)bh * Nn + qg];
        float m1 = pm[(size_t)(16 + bh) * Nn + qg];
        float l0 = pl[(size_t)bh * Nn + qg];
        float l1 = pl[(size_t)(16 + bh) * Nn + qg];
        float M = fmaxf(m0, m1);
        float w0 = fexp2(m0 - M), w1 = fexp2(m1 - M);
        float inv = 1.0f / (l0 * w0 + l1 * w1);
        f0a[t] = w0 * inv; f1a[t] = w1 * inv;
    }
    __syncthreads();
    int wv = t >> 6, lane = t & 63;
    #pragma unroll
    for (int i = 0; i < 16; ++i) {
        int d = wv * 16 + i;
        float c0 = __uint_as_float((u32)pc[((size_t)bh * 64 + d) * Nn + q0 + lane] << 16);
        float c1 = __uint_as_float((u32)pc[((size_t)(16 + bh) * 64 + d) * Nn + q0 + lane] << 16);
        trans[lane][d] = c0 * f0a[lane] + c1 * f1a[lane];
    }
    __syncthreads();
    int q = t >> 2, dg = t & 3;
    int b = bh >> 2, h = bh & 3;
    const float* tr = &trans[q][dg * 16];
    uint4 pa, pb;
    pa.x = cvtpk(tr[0], tr[1]);  pa.y = cvtpk(tr[2], tr[3]);
    pa.z = cvtpk(tr[4], tr[5]);  pa.w = cvtpk(tr[6], tr[7]);
    pb.x = cvtpk(tr[8], tr[9]);  pb.y = cvtpk(tr[10], tr[11]);
    pb.z = cvtpk(tr[12], tr[13]); pb.w = cvtpk(tr[14], tr[15]);
    u16* op = ctxOut + ((size_t)b * Nn + q0 + q) * Dd + h * 64 + dg * 16;
    *(uint4*)op = pa;
    *(uint4*)(op + 8) = pb;
}

extern "C" void kernel_launch(void* const* d_in, const int* in_sizes, int n_in,
                              void* d_out, int out_size, void* d_ws, size_t ws_size,
                              hipStream_t stream) {
    (void)in_sizes; (void)n_in; (void)out_size; (void)ws_size;
    const float* tokens     = (const float*)d_in[0];
    const float* importance = (const float*)d_in[1];
    const float* n1w = (const float*)d_in[2];
    const float* n1b = (const float*)d_in[3];
    const float* Wq  = (const float*)d_in[4];
    const float* bq  = (const float*)d_in[5];
    const float* Wk  = (const float*)d_in[6];
    const float* bk  = (const float*)d_in[7];
    const float* Wv  = (const float*)d_in[8];
    const float* bv  = (const float*)d_in[9];
    const float* Wo  = (const float*)d_in[10];
    const float* bo  = (const float*)d_in[11];
    const float* n2w = (const float*)d_in[12];
    const float* n2b = (const float*)d_in[13];
    const float* W1  = (const float*)d_in[14];
    const float* b1  = (const float*)d_in[15];
    const float* W2  = (const float*)d_in[16];
    const float* b2  = (const float*)d_in[17];
    float* out = (float*)d_out;

    char* ws = (char*)d_ws;
    const size_t MB = (size_t)1 << 20;
    // Buffer sizes: xln/qb/kb/vT/ctx/yln 8MB each; pc 16MB; hbuf 16MB.
    // Sequential reuse (single stream): yln reuses xln (dead after QKV GEMM);
    // hbuf reuses qb+kb (dead after attn); x2 = d_out (dead until MODE 1).
    u16* xln   = (u16*)(ws);                    // 0..8MB   (later: yln)
    u16* qb    = (u16*)(ws + 8 * MB);           // 8..16MB  (later: hbuf lo)
    u16* kb    = (u16*)(ws + 16 * MB);          // 16..24MB (later: hbuf hi)
    u16* vT    = (u16*)(ws + 24 * MB);          // 24..32MB
    u16* ctx   = (u16*)(ws + 32 * MB);          // 32..40MB
    u16* pc    = (u16*)(ws + 40 * MB);          // 40..56MB [kvh*16+bh][64 d][4096 q]
    float* pm  = (float*)(ws + 56 * MB);        // 512KB
    float* pl  = (float*)(ws + 56 * MB + 524288);
    u16* WqkvT = (u16*)(ws + 57 * MB);          // 384KB
    u16* WoT   = (u16*)(ws + 57 * MB + 393216);
    u16* W1T   = (u16*)(ws + 57 * MB + 393216 + 131072);
    u16* W2T   = (u16*)(ws + 57 * MB + 393216 + 131072 + 262144);
    u32* impPk = (u32*)(ws + 57 * MB + 393216 + 131072 + 262144 + 262144);
    u16* yln   = xln;                           // reuse (xln dead after QKV)
    u16* hbuf  = qb;                            // reuse 16MB (qb+kb dead after attn)
    float* x2  = out;                           // reuse d_out as x2 scratch

    prep_kernel<<<2112, 256, 0, stream>>>(Wq, Wk, Wv, Wo, W1, W2, importance,
                                          WqkvT, WoT, W1T, W2T, impPk);
    ln_kernel<<<4096, 256, 0, stream>>>(tokens, n1w, n1b, xln);
    gemm_bt<0, 256><<<dim3(6, 128), 256, 0, stream>>>(xln, WqkvT, bq, bk, bv,
                                                      nullptr, nullptr, qb, kb, vT);
    attn_kernel<<<1024, 256, 0, stream>>>(qb, kb, vT, impPk, pc, pm, pl);
    merge_kernel<<<1024, 256, 0, stream>>>(pc, pm, pl, ctx);
    gemm_bt<1, 256><<<dim3(2, 128), 256, 0, stream>>>(ctx, WoT, bo, nullptr, nullptr,
                                                      tokens, x2, nullptr, nullptr, nullptr);
    ln_kernel<<<4096, 256, 0, stream>>>(x2, n2w, n2b, yln);
    gemm_bt<2, 256><<<dim3(4, 128), 256, 0, stream>>>(yln, W1T, b1, nullptr, nullptr,
                                                      nullptr, nullptr, hbuf, nullptr, nullptr);
    gemm_bt<3, 512><<<dim3(2, 128), 256, 0, stream>>>(hbuf, W2T, b2, nullptr, nullptr,
                                                      x2, out, nullptr, nullptr, nullptr);
}